// Round 4
// baseline (103.964 us; speedup 1.0000x reference)
//
#include <hip/hip_runtime.h>
#include <math.h>
#include <stdint.h>

// n=256 samples, d=64, fp32 in/out. J-path bf16 MFMA.
//   K[m][l] = (1-h^2)[m] W1[m][l];  sKT[l][m] = K[m][l] (bf16), row 64 = h
//   W2sB[i][j][m] = bf16(W2[(i,j)][m] + W2[(j,i)][m])  (symmetric in i,j)
//   slab-frag af[t] (rows of W2s_i) and sKT-frag bf[t] are BOTH valid as A or B:
//     C1 = mfma(A=af[tr], B=bf[tc]) -> Ji[j][l]       (j=row, l=col)
//     C2 = mfma(A=bf[tr], B=af[tc]) -> Ji[l][j]       at the SAME (lane,reg)!
//   => q[l] += v_i * v_j * C1^2 * C2 fully in-register; no LDS transpose,
//      no barriers in the i-loop.
// R4: 512 threads (8 waves, 2 waves/SIMD) — R3 showed all pipes <25% busy at
//   1 wave/SIMD (pure MFMA/VALU latency stalls). Each wave owns 8 i's.
//   g-row i via ext B-frag (sKT row 64 = h); g += b2 + b2^T; 12 Jacobi sweeps;
//   out = v@W3[:,:64]^T + 0.5 z@W3[:,64:]^T.

typedef short short8 __attribute__((ext_vector_type(8)));
typedef float f32x4 __attribute__((ext_vector_type(4)));

__device__ __forceinline__ unsigned short f2bf(float f) {
  unsigned int u = __builtin_bit_cast(unsigned int, f);
  u += 0x7fffu + ((u >> 16) & 1u);
  return (unsigned short)(u >> 16);
}

__device__ __forceinline__ short8 as_short8(uint4 u) {
  union { uint4 a; short8 b; } cv; cv.a = u; return cv.b;
}

__global__ __launch_bounds__(256) void prep_w2s_kernel(const float* __restrict__ W2,
                                                       unsigned short* __restrict__ W2sB) {
  int idx = blockIdx.x * 256 + threadIdx.x;           // [i][j][m]
  int i = idx >> 12, j = (idx >> 6) & 63, m = idx & 63;
  W2sB[idx] = f2bf(W2[(((i << 6) + j) << 6) + m] + W2[(((j << 6) + i) << 6) + m]);
}

__global__ __launch_bounds__(512, 2) void conn_kernel(
    const float* __restrict__ x, const float* __restrict__ v,
    const float* __restrict__ W1, const float* __restrict__ b1,
    const float* __restrict__ b2, const float* __restrict__ W3,
    const unsigned short* __restrict__ W2sB, float* __restrict__ out) {
  __shared__ __align__(16) unsigned short sKT[80 * 80];  // rows 0-63 = K^T, 64 = h, 65-79 = 0
  __shared__ __align__(16) float sg[64 * 68];            // g, stride 68 (f32x4-aligned stores)
  __shared__ float spq[8][64];
  __shared__ __align__(16) float sh[64], sv[64], sx[64], sq[64], sz[64];

  const int n = blockIdx.x, t = threadIdx.x;
  const int wv = t >> 6, lane = t & 63, ln15 = lane & 15, quad = lane >> 4;

  if (t < 64) { sx[t] = x[(n << 6) + t]; sv[t] = v[(n << 6) + t]; }
  for (int e = t; e < 6400; e += 512) sKT[e] = 0;
  __syncthreads();

  if (t < 64) {
    float acc = b1[t];
    #pragma unroll 8
    for (int l = 0; l < 64; ++l) acc += sx[l] * W1[(t << 6) + l];
    sh[t] = tanhf(acc);
  }
  __syncthreads();

  for (int e = t; e < 4096; e += 512) {
    int m = e & 63, l = e >> 6;
    float hm = sh[m];
    sKT[l * 80 + m] = f2bf((1.f - hm * hm) * W1[(m << 6) + l]);
  }
  if (t < 64) sKT[64 * 80 + t] = f2bf(sh[t]);
  __syncthreads();

  // sKT frags: tiles 0..3 dual-use (A for C2 row-tile / B for C1 col-tile), tile 4 = ext (h)
  short8 bf[5][2];
  #pragma unroll
  for (int tc = 0; tc < 5; ++tc)
    #pragma unroll
    for (int ks = 0; ks < 2; ++ks)
      bf[tc][ks] = *(const short8*)&sKT[(tc * 16 + ln15) * 80 + ks * 32 + quad * 8];

  f32x4 svj[4];
  #pragma unroll
  for (int tr = 0; tr < 4; ++tr) svj[tr] = *(const f32x4*)&sv[tr * 16 + quad * 4];

  float qacc[4] = {0.f, 0.f, 0.f, 0.f};

  // Wave wv owns i in [8*wv, 8*wv+8). Slab frags: dual-use A(C1)/B(C2).
  const int foff = (ln15 << 6) + quad * 8;  // within-slab frag offset
  const unsigned short* sbase = W2sB + ((size_t)(8 * wv) << 12);

  uint4 af[4][2], afn[4][2];
  #pragma unroll
  for (int tc = 0; tc < 4; ++tc) {
    af[tc][0] = *(const uint4*)(sbase + (tc << 10) + foff);
    af[tc][1] = *(const uint4*)(sbase + (tc << 10) + foff + 32);
  }

  for (int ii = 0; ii < 8; ++ii) {
    const unsigned short* spn = W2sB + ((size_t)(8 * wv + ((ii + 1) & 7)) << 12);
    #pragma unroll
    for (int tc = 0; tc < 4; ++tc) {
      afn[tc][0] = *(const uint4*)(spn + (tc << 10) + foff);
      afn[tc][1] = *(const uint4*)(spn + (tc << 10) + foff + 32);
    }
    const int i = 8 * wv + ii;
    const float vi = sv[i];

    #pragma unroll
    for (int tr = 0; tr < 4; ++tr) {
      short8 a0 = as_short8(af[tr][0]), a1 = as_short8(af[tr][1]);
      f32x4 c1[4], c2[4], ce;
      #pragma unroll
      for (int tc = 0; tc < 4; ++tc) {
        f32x4 z4 = {0.f, 0.f, 0.f, 0.f};
        f32x4 u = __builtin_amdgcn_mfma_f32_16x16x32_bf16(a0, bf[tc][0], z4, 0, 0, 0);
        c1[tc]  = __builtin_amdgcn_mfma_f32_16x16x32_bf16(a1, bf[tc][1], u, 0, 0, 0);
        f32x4 w = __builtin_amdgcn_mfma_f32_16x16x32_bf16(bf[tr][0], as_short8(af[tc][0]), z4, 0, 0, 0);
        c2[tc]  = __builtin_amdgcn_mfma_f32_16x16x32_bf16(bf[tr][1], as_short8(af[tc][1]), w, 0, 0, 0);
      }
      {
        f32x4 z4 = {0.f, 0.f, 0.f, 0.f};
        f32x4 u = __builtin_amdgcn_mfma_f32_16x16x32_bf16(a0, bf[4][0], z4, 0, 0, 0);
        ce      = __builtin_amdgcn_mfma_f32_16x16x32_bf16(a1, bf[4][1], u, 0, 0, 0);
      }
      if (ln15 == 0)  // g[i][j], j = 16*tr + 4*quad + r
        *(f32x4*)&sg[i * 68 + tr * 16 + quad * 4] = ce;

      #pragma unroll
      for (int tc = 0; tc < 4; ++tc) {
        float s = 0.f;
        #pragma unroll
        for (int r = 0; r < 4; ++r) {
          float a = c1[tc][r];
          s = fmaf(a * a * c2[tc][r], svj[tr][r], s);
        }
        qacc[tc] = fmaf(s, vi, qacc[tc]);
      }
    }
    #pragma unroll
    for (int tc = 0; tc < 4; ++tc) { af[tc][0] = afn[tc][0]; af[tc][1] = afn[tc][1]; }
  }

  // reduce qacc over quads (rows j), publish per-wave partial q
  #pragma unroll
  for (int tc = 0; tc < 4; ++tc) {
    float s = qacc[tc];
    s += __shfl_xor(s, 16, 64);
    s += __shfl_xor(s, 32, 64);
    if (quad == 0) spq[wv][tc * 16 + ln15] = s;
  }
  __syncthreads();  // first block-wide sync since setup

  for (int e = t; e < 4096; e += 512) {   // g += b2 + b2^T
    int r = e >> 6, c = e & 63;
    sg[r * 68 + c] += b2[(r << 6) + c] + b2[(c << 6) + r];
  }
  __syncthreads();

  if (t < 64) {
    float s = 0.f;
    #pragma unroll
    for (int w2 = 0; w2 < 8; ++w2) s += spq[w2][t];
    sq[t] = s;
    sz[t] = s / sg[t * 68 + t];   // Jacobi init
  }
  __syncthreads();

  // Jacobi: z' = z + (q - g z)/diag; waves 0-3 compute (row r = 16*wv+ln15,
  // col-group = quad), waves 4-7 just hit the barriers.
  {
    const int r = 16 * (wv & 3) + ln15;
    const float* grow = &sg[r * 68];
    const float dinv = 1.f / grow[r];
    const float qr = sq[r];
    for (int it = 0; it < 12; ++it) {
      float zr = 0.f;
      if (t < 256) {
        float p = 0.f;
        #pragma unroll
        for (int cc = 0; cc < 16; ++cc) {
          int cidx = quad * 16 + cc;
          p += grow[cidx] * sz[cidx];
        }
        p += __shfl_xor(p, 16, 64);
        p += __shfl_xor(p, 32, 64);
        if (quad == 0) zr = sz[r] + (qr - p) * dinv;
      }
      __syncthreads();
      if (t < 256 && quad == 0) sz[r] = zr;
      __syncthreads();
    }
  }

  if (t < 64) {
    float accv = 0.f, accd = 0.f;
    #pragma unroll 8
    for (int c = 0; c < 64; ++c) {
      accv += sv[c] * W3[(t << 7) + c];
      accd += sz[c] * W3[(t << 7) + 64 + c];
    }
    out[(n << 6) + t] = accv + 0.5f * accd;
  }
}

extern "C" void kernel_launch(void* const* d_in, const int* in_sizes, int n_in,
                              void* d_out, int out_size, void* d_ws, size_t ws_size,
                              hipStream_t stream) {
  (void)in_sizes; (void)n_in; (void)out_size; (void)ws_size;
  const float* x  = (const float*)d_in[1];
  const float* v  = (const float*)d_in[2];
  const float* W1 = (const float*)d_in[3];
  const float* b1 = (const float*)d_in[4];
  const float* W2 = (const float*)d_in[5];
  const float* b2 = (const float*)d_in[6];
  const float* W3 = (const float*)d_in[7];
  unsigned short* W2sB = (unsigned short*)d_ws;  // 64*64*64 bf16 = 512 KB

  hipLaunchKernelGGL(prep_w2s_kernel, dim3(1024), dim3(256), 0, stream, W2, W2sB);
  hipLaunchKernelGGL(conn_kernel, dim3(256), dim3(512), 0, stream,
                     x, v, W1, b1, b2, W3, W2sB, (float*)d_out);
}